// Round 16
// baseline (108.622 us; speedup 1.0000x reference)
//
#include <hip/hip_runtime.h>

// Geometry constants (from the reference)
constexpr int   CC      = 128;               // channels per slice (LAST_DIM)
constexpr int   WSTRIDE = 9 * 128;           // floats per W step  (1152)
constexpr int   HSTRIDE = 96 * WSTRIDE;      // floats per H step
constexpr long  BSTRIDE = 64L * HSTRIDE;     // floats per batch image
constexpr int   RUN     = 4;                 // consecutive sorted ranks per wave

// ---- shared box math -------------------------------------------------------
__device__ __forceinline__ void box_setup(const float* __restrict__ rois,
                                          int n, int wid,
                                          int& b, float& ybase, float& ystep,
                                          float& xbase, float& xstep) {
  const float r0  = rois[n * 5 + 0];
  const float rx1 = rois[n * 5 + 1];
  const float ry1 = rois[n * 5 + 2];
  const float rx2 = rois[n * 5 + 3];
  const float ry2 = rois[n * 5 + 4];
  b = (int)r0;

  const float x1 = rx1 / 1536.0f;
  const float y1 = ry1 / 1024.0f;
  const float x2 = rx2 / 1536.0f;
  const float y2 = ry2 / 1024.0f;

  const float bin_w = (x2 - x1) / 3.0f;
  const float bin_h = y2 - y1 / 3.0f;        // faithful to reference (precedence bug kept)

  const int ih = wid / 3;
  const int iw = wid - 3 * ih;

  const float by1 = y1 + (float)ih * bin_h;
  const float bx1 = x1 + (float)iw * bin_w;
  const float by2 = y1 + (float)(ih + 1) * bin_h;
  const float bx2 = x1 + (float)(iw + 1) * bin_h;  // faithful: bin_h here (reference bug)

  ystep = ((by2 - by1) * 63.0f) / 5.0f;
  xstep = ((bx2 - bx1) * 95.0f) / 5.0f;
  ybase = by1 * 63.0f;
  xbase = bx1 * 95.0f;
}

// ---- R6 accumulate: half-wave pairing, float4 channels, batched row loads -
// lane = half*32 + cl : half selects even/odd x-samples, cl selects 4 channels.
__device__ __forceinline__ void subbox_accum4(const float* __restrict__ feat,
                                              const float* __restrict__ rois,
                                              int n, int wid, int lane,
                                              float4& acc) {
  int b; float ybase, ystep, xbase, xstep;
  box_setup(rois, n, wid, b, ybase, ystep, xbase, xstep);

  const int half = lane >> 5;                // 0: sx even, 1: sx odd
  const int cl   = lane & 31;                // channel quad 4*cl..4*cl+3

  // per-lane x info for sx = 2k+half, k=0..2  (branchless: mask multiply)
  int   xo0[3], xo1[3];
  float lx[3], mx[3];
#pragma unroll
  for (int k = 0; k < 3; ++k) {
    const float xs = xbase + (float)(2 * k + half) * xstep;
    mx[k] = (xs >= 0.0f && xs <= 95.0f) ? 1.0f : 0.0f;
    const float xf = floorf(xs);
    lx[k] = xs - xf;
    int xi = (int)xf;
    xi = xi < 0 ? 0 : (xi > 95 ? 95 : xi);
    const int xj = (xi + 1 > 95) ? 95 : xi + 1;
    xo0[k] = xi * WSTRIDE;
    xo1[k] = xj * WSTRIDE;
  }

  const float* fb = feat + (size_t)b * BSTRIDE + wid * CC + 4 * cl;

#pragma unroll
  for (int sy = 0; sy < 6; ++sy) {
    const float ys = ybase + (float)sy * ystep;
    if (!((ys >= 0.0f) && (ys <= 63.0f))) continue;   // wave-uniform row skip
    const float yf = floorf(ys);
    const float ly = ys - yf;
    int yi = (int)yf;
    yi = yi < 0 ? 0 : (yi > 63 ? 63 : yi);
    const int yj = (yi + 1 > 63) ? 63 : yi + 1;
    const float* row0 = fb + (size_t)yi * HSTRIDE;
    const float* row1 = fb + (size_t)yj * HSTRIDE;

    // issue all 12 independent float4 loads for this row, then compute
    float4 v00[3], v01[3], v10[3], v11[3];
#pragma unroll
    for (int k = 0; k < 3; ++k) {
      v00[k] = *(const float4*)(row0 + xo0[k]);
      v01[k] = *(const float4*)(row0 + xo1[k]);
      v10[k] = *(const float4*)(row1 + xo0[k]);
      v11[k] = *(const float4*)(row1 + xo1[k]);
    }
#pragma unroll
    for (int k = 0; k < 3; ++k) {
      const float l = lx[k], m = mx[k];
      const float oly = 1.0f - ly;
      const float t0 = v00[k].x * (1.0f - l) + v01[k].x * l;
      const float t1 = v00[k].y * (1.0f - l) + v01[k].y * l;
      const float t2 = v00[k].z * (1.0f - l) + v01[k].z * l;
      const float t3 = v00[k].w * (1.0f - l) + v01[k].w * l;
      const float u0 = v10[k].x * (1.0f - l) + v11[k].x * l;
      const float u1 = v10[k].y * (1.0f - l) + v11[k].y * l;
      const float u2 = v10[k].z * (1.0f - l) + v11[k].z * l;
      const float u3 = v10[k].w * (1.0f - l) + v11[k].w * l;
      acc.x += m * (t0 * oly + u0 * ly);
      acc.y += m * (t1 * oly + u1 * ly);
      acc.z += m * (t2 * oly + u2 * ly);
      acc.w += m * (t3 * oly + u3 * ly);
    }
  }
}

// ---- phase 0: spatial sort of ROI indices (single block, bitonic, 2048) ---
__global__ __launch_bounds__(1024)
void rroi_sort_kernel(const float* __restrict__ rois, int* __restrict__ order,
                      int N) {
  __shared__ unsigned s[2048];
  const int t = threadIdx.x;
  for (int i = t; i < 2048; i += 1024) {
    unsigned key;
    if (i < N) {
      const int   bi = (int)rois[i * 5 + 0];
      const float cx = (rois[i * 5 + 1] + rois[i * 5 + 3]) * 0.5f * (96.0f / 1536.0f);
      const float cy = (rois[i * 5 + 2] + rois[i * 5 + 4]) * 0.5f * (64.0f / 1024.0f);
      int cyi = (int)cy; cyi = cyi < 0 ? 0 : (cyi > 63 ? 63 : cyi);
      int cxi = (int)cx; cxi = cxi < 0 ? 0 : (cxi > 95 ? 95 : cxi);
      key = (unsigned)((bi * 64 + cyi) * 96 + cxi);      // < 2^15
    } else {
      key = 0xFFFFFu;
    }
    s[i] = (key << 11) | (unsigned)i;                    // unique -> deterministic
  }
  __syncthreads();
  for (int k = 2; k <= 2048; k <<= 1) {
    for (int j = k >> 1; j > 0; j >>= 1) {
      for (int i = t; i < 2048; i += 1024) {
        const int ixj = i ^ j;
        if (ixj > i) {
          const unsigned a = s[i], b = s[ixj];
          const bool up = (i & k) == 0;
          if ((a > b) == up) { s[i] = b; s[ixj] = a; }
        }
      }
      __syncthreads();
    }
  }
  for (int i = t; i < 2048; i += 1024)
    if (i < N) order[i] = (int)(s[i] & 0x7FFu);
}

// ---- phase 1: one wave per block; RUN consecutive sorted ranks per wave ---
// Consecutive sorted ROIs overlap spatially ~80%, so items 2..RUN of a run
// hit the wave's CU L1 -> line-fills (the MSHR-bound resource) drop ~2.5x.
__global__ __launch_bounds__(64)
void rroi_partial_kernel(const float* __restrict__ feat,
                         const float* __restrict__ rois,
                         const int* __restrict__ order,
                         float* __restrict__ ws, int N,
                         int runsPerPlane, int chunk) {
  const int lane  = threadIdx.x;
  const int local = blockIdx.x >> 3;
  if (local >= chunk) return;
  const int runIdx = (int)(blockIdx.x & 7) * chunk + local;  // XCD-chunked, plane-major
  const int totalRuns = 9 * runsPerPlane;
  if (runIdx >= totalRuns) return;
  const int wid = runIdx / runsPerPlane;
  const int r0  = (runIdx - wid * runsPerPlane) * RUN;

#pragma unroll
  for (int r = 0; r < RUN; ++r) {
    const int rank = r0 + r;
    if (rank >= N) break;
    const int n = order[rank];                          // spatially sorted ROI

    float4 acc = make_float4(0.f, 0.f, 0.f, 0.f);
    subbox_accum4(feat, rois, n, wid, lane, acc);

    // combine even/odd sample halves
    acc.x += __shfl_xor(acc.x, 32, 64);
    acc.y += __shfl_xor(acc.y, 32, 64);
    acc.z += __shfl_xor(acc.z, 32, 64);
    acc.w += __shfl_xor(acc.w, 32, 64);

    if ((lane >> 5) == 0) {
      float* p = ws + ((size_t)n * 9 + wid) * CC + 4 * (lane & 31);
      *(float4*)p = acc;
    }
  }
}

// ---- phase 2: reduce 9 partials per ROI (4 ROIs per block) ----------------
__global__ __launch_bounds__(512)
void rroi_reduce_kernel(const float* __restrict__ ws,
                        float* __restrict__ out, int N) {
  const int n = blockIdx.x * 4 + (threadIdx.x >> 7);
  if (n >= N) return;
  const int c = threadIdx.x & 127;
  const float* p = ws + (size_t)n * 9 * CC + c;
  float s = 0.0f;
#pragma unroll
  for (int w = 0; w < 9; ++w) s += p[w * CC];
  out[(size_t)n * CC + c] = s * (1.0f / 324.0f);  // (/9 sub-boxes)*(/36 mean)
}

// ---- fallback: monolithic single-kernel (no ws needed) --------------------
__global__ __launch_bounds__(576)
void rroi_pool_kernel(const float* __restrict__ feat,
                      const float* __restrict__ rois,
                      float* __restrict__ out, int N) {
  const int n = blockIdx.x;
  const int wid  = threadIdx.x >> 6;
  const int lane = threadIdx.x & 63;
  __shared__ float partial[9][CC];

  float4 acc = make_float4(0.f, 0.f, 0.f, 0.f);
  subbox_accum4(feat, rois, n, wid, lane, acc);

  acc.x += __shfl_xor(acc.x, 32, 64);
  acc.y += __shfl_xor(acc.y, 32, 64);
  acc.z += __shfl_xor(acc.z, 32, 64);
  acc.w += __shfl_xor(acc.w, 32, 64);

  if ((lane >> 5) == 0) {
    const int cl = lane & 31;
    partial[wid][4 * cl + 0] = acc.x;
    partial[wid][4 * cl + 1] = acc.y;
    partial[wid][4 * cl + 2] = acc.z;
    partial[wid][4 * cl + 3] = acc.w;
  }
  __syncthreads();

  if (threadIdx.x < CC) {
    float s = 0.0f;
#pragma unroll
    for (int w = 0; w < 9; ++w) s += partial[w][threadIdx.x];
    out[(size_t)n * CC + threadIdx.x] = s * (1.0f / 324.0f);
  }
}

extern "C" void kernel_launch(void* const* d_in, const int* in_sizes, int n_in,
                              void* d_out, int out_size, void* d_ws, size_t ws_size,
                              hipStream_t stream) {
  const float* feat = (const float*)d_in[0];   // (4,64,96,1152) f32
  const float* rois = (const float*)d_in[1];   // (2048,5) f32
  float* out = (float*)d_out;                  // (1,2048,128) f32
  const int N = in_sizes[1] / 5;

  const size_t need = (size_t)N * 9 * CC * sizeof(float) + (size_t)N * sizeof(int);
  if (ws_size >= need && N <= 2048) {
    float* ws    = (float*)d_ws;
    int*   order = (int*)(ws + (size_t)N * 9 * CC);
    const int runsPerPlane = (N + RUN - 1) / RUN;        // 512 for N=2048
    const int totalRuns    = 9 * runsPerPlane;           // 4608
    const int chunk        = (totalRuns + 7) / 8;        // runs per XCD
    const int blocks       = chunk * 8;
    rroi_sort_kernel<<<1, 1024, 0, stream>>>(rois, order, N);
    rroi_partial_kernel<<<blocks, 64, 0, stream>>>(feat, rois, order, ws, N,
                                                   runsPerPlane, chunk);
    rroi_reduce_kernel<<<(N + 3) / 4, 512, 0, stream>>>(ws, out, N);
  } else {
    rroi_pool_kernel<<<N, 576, 0, stream>>>(feat, rois, out, N);
  }
}

// Round 17
// 78.680 us; speedup vs baseline: 1.3806x; 1.3806x over previous
//
#include <hip/hip_runtime.h>

// Geometry constants (from the reference)
constexpr int   CC      = 128;               // channels per slice (LAST_DIM)
constexpr int   WSTRIDE = 9 * 128;           // floats per W step  (1152)
constexpr int   HSTRIDE = 96 * WSTRIDE;      // floats per H step
constexpr long  BSTRIDE = 64L * HSTRIDE;     // floats per batch image

// ---- shared box math -------------------------------------------------------
__device__ __forceinline__ void box_setup(const float* __restrict__ rois,
                                          int n, int wid,
                                          int& b, float& ybase, float& ystep,
                                          float& xbase, float& xstep) {
  const float r0  = rois[n * 5 + 0];
  const float rx1 = rois[n * 5 + 1];
  const float ry1 = rois[n * 5 + 2];
  const float rx2 = rois[n * 5 + 3];
  const float ry2 = rois[n * 5 + 4];
  b = (int)r0;

  const float x1 = rx1 / 1536.0f;
  const float y1 = ry1 / 1024.0f;
  const float x2 = rx2 / 1536.0f;
  const float y2 = ry2 / 1024.0f;

  const float bin_w = (x2 - x1) / 3.0f;
  const float bin_h = y2 - y1 / 3.0f;        // faithful to reference (precedence bug kept)

  const int ih = wid / 3;
  const int iw = wid - 3 * ih;

  const float by1 = y1 + (float)ih * bin_h;
  const float bx1 = x1 + (float)iw * bin_w;
  const float by2 = y1 + (float)(ih + 1) * bin_h;
  const float bx2 = x1 + (float)(iw + 1) * bin_h;  // faithful: bin_h here (reference bug)

  ystep = ((by2 - by1) * 63.0f) / 5.0f;
  xstep = ((bx2 - bx1) * 95.0f) / 5.0f;
  ybase = by1 * 63.0f;
  xbase = bx1 * 95.0f;
}

// raw global_load_dwordx4: compiler cannot recycle the dst reg before use,
// and does NOT insert its own waitcnt for it -> true 12-deep MLP per row.
#define GLOAD4(dst, ptr)                                              \
  asm volatile("global_load_dwordx4 %0, %1, off"                      \
               : "=v"(dst) : "v"(ptr))

// ---- forced-MLP accumulate: 12 asm loads in flight per row ----------------
// lane = half*32 + cl : half selects even/odd x-samples, cl selects 4 channels.
__device__ __forceinline__ void subbox_accum4(const float* __restrict__ feat,
                                              const float* __restrict__ rois,
                                              int n, int wid, int lane,
                                              float4& acc) {
  int b; float ybase, ystep, xbase, xstep;
  box_setup(rois, n, wid, b, ybase, ystep, xbase, xstep);

  const int half = lane >> 5;                // 0: sx even, 1: sx odd
  const int cl   = lane & 31;                // channel quad 4*cl..4*cl+3

  // per-lane x info for sx = 2k+half, k=0..2  (branchless: mask multiply)
  int   xo0[3], xo1[3];
  float lx[3], mx[3];
#pragma unroll
  for (int k = 0; k < 3; ++k) {
    const float xs = xbase + (float)(2 * k + half) * xstep;
    mx[k] = (xs >= 0.0f && xs <= 95.0f) ? 1.0f : 0.0f;
    const float xf = floorf(xs);
    lx[k] = xs - xf;
    int xi = (int)xf;
    xi = xi < 0 ? 0 : (xi > 95 ? 95 : xi);
    const int xj = (xi + 1 > 95) ? 95 : xi + 1;
    xo0[k] = xi * WSTRIDE;
    xo1[k] = xj * WSTRIDE;
  }

  const float* fb = feat + (size_t)b * BSTRIDE + wid * CC + 4 * cl;

#pragma unroll
  for (int sy = 0; sy < 6; ++sy) {
    const float ys = ybase + (float)sy * ystep;
    if (!((ys >= 0.0f) && (ys <= 63.0f))) continue;   // wave-uniform row skip
    const float yf = floorf(ys);
    const float ly = ys - yf;
    int yi = (int)yf;
    yi = yi < 0 ? 0 : (yi > 63 ? 63 : yi);
    const int yj = (yi + 1 > 63) ? 63 : yi + 1;
    const float* row0 = fb + (size_t)yi * HSTRIDE;
    const float* row1 = fb + (size_t)yj * HSTRIDE;

    // issue ALL 12 loads before any wait: forced 12-deep MLP
    float4 v00a, v00b, v00c, v01a, v01b, v01c;
    float4 v10a, v10b, v10c, v11a, v11b, v11c;
    GLOAD4(v00a, row0 + xo0[0]);
    GLOAD4(v00b, row0 + xo0[1]);
    GLOAD4(v00c, row0 + xo0[2]);
    GLOAD4(v01a, row0 + xo1[0]);
    GLOAD4(v01b, row0 + xo1[1]);
    GLOAD4(v01c, row0 + xo1[2]);
    GLOAD4(v10a, row1 + xo0[0]);
    GLOAD4(v10b, row1 + xo0[1]);
    GLOAD4(v10c, row1 + xo0[2]);
    GLOAD4(v11a, row1 + xo1[0]);
    GLOAD4(v11b, row1 + xo1[1]);
    GLOAD4(v11c, row1 + xo1[2]);
    asm volatile("s_waitcnt vmcnt(0)" ::: "memory");
    __builtin_amdgcn_sched_barrier(0);       // rule #18: keep FMAs below the wait

    const float oly = 1.0f - ly;
    const float4 v00[3] = {v00a, v00b, v00c};
    const float4 v01[3] = {v01a, v01b, v01c};
    const float4 v10[3] = {v10a, v10b, v10c};
    const float4 v11[3] = {v11a, v11b, v11c};
#pragma unroll
    for (int k = 0; k < 3; ++k) {
      const float l = lx[k], m = mx[k];
      const float t0 = v00[k].x * (1.0f - l) + v01[k].x * l;
      const float t1 = v00[k].y * (1.0f - l) + v01[k].y * l;
      const float t2 = v00[k].z * (1.0f - l) + v01[k].z * l;
      const float t3 = v00[k].w * (1.0f - l) + v01[k].w * l;
      const float u0 = v10[k].x * (1.0f - l) + v11[k].x * l;
      const float u1 = v10[k].y * (1.0f - l) + v11[k].y * l;
      const float u2 = v10[k].z * (1.0f - l) + v11[k].z * l;
      const float u3 = v10[k].w * (1.0f - l) + v11[k].w * l;
      acc.x += m * (t0 * oly + u0 * ly);
      acc.y += m * (t1 * oly + u1 * ly);
      acc.z += m * (t2 * oly + u2 * ly);
      acc.w += m * (t3 * oly + u3 * ly);
    }
  }
}

// ---- phase 0: spatial sort of ROI indices (single block, bitonic, 2048) ---
__global__ __launch_bounds__(1024)
void rroi_sort_kernel(const float* __restrict__ rois, int* __restrict__ order,
                      int N) {
  __shared__ unsigned s[2048];
  const int t = threadIdx.x;
  for (int i = t; i < 2048; i += 1024) {
    unsigned key;
    if (i < N) {
      const int   bi = (int)rois[i * 5 + 0];
      const float cx = (rois[i * 5 + 1] + rois[i * 5 + 3]) * 0.5f * (96.0f / 1536.0f);
      const float cy = (rois[i * 5 + 2] + rois[i * 5 + 4]) * 0.5f * (64.0f / 1024.0f);
      int cyi = (int)cy; cyi = cyi < 0 ? 0 : (cyi > 63 ? 63 : cyi);
      int cxi = (int)cx; cxi = cxi < 0 ? 0 : (cxi > 95 ? 95 : cxi);
      key = (unsigned)((bi * 64 + cyi) * 96 + cxi);      // < 2^15
    } else {
      key = 0xFFFFFu;
    }
    s[i] = (key << 11) | (unsigned)i;                    // unique -> deterministic
  }
  __syncthreads();
  for (int k = 2; k <= 2048; k <<= 1) {
    for (int j = k >> 1; j > 0; j >>= 1) {
      for (int i = t; i < 2048; i += 1024) {
        const int ixj = i ^ j;
        if (ixj > i) {
          const unsigned a = s[i], b = s[ixj];
          const bool up = (i & k) == 0;
          if ((a > b) == up) { s[i] = b; s[ixj] = a; }
        }
      }
      __syncthreads();
    }
  }
  for (int i = t; i < 2048; i += 1024)
    if (i < N) order[i] = (int)(s[i] & 0x7FFu);
}

// ---- phase 1: one wave per block, XCD-chunked planes ----------------------
__global__ __launch_bounds__(64, 1)
void rroi_partial_kernel(const float* __restrict__ feat,
                         const float* __restrict__ rois,
                         const int* __restrict__ order,
                         float* __restrict__ ws, int N, int chunk) {
  const int lane  = threadIdx.x;
  const int local = blockIdx.x >> 3;
  if (local >= chunk) return;
  const int j = (int)(blockIdx.x & 7) * chunk + local;   // XCD x sweeps chunk x
  const int total = N * 9;
  if (j >= total) return;
  const int wid  = j / N;                                // same-wid contiguous per XCD
  const int rank = j - wid * N;
  const int n    = order[rank];                          // spatially sorted ROI

  float4 acc = make_float4(0.f, 0.f, 0.f, 0.f);
  subbox_accum4(feat, rois, n, wid, lane, acc);

  // combine even/odd sample halves
  acc.x += __shfl_xor(acc.x, 32, 64);
  acc.y += __shfl_xor(acc.y, 32, 64);
  acc.z += __shfl_xor(acc.z, 32, 64);
  acc.w += __shfl_xor(acc.w, 32, 64);

  if ((lane >> 5) == 0) {
    float* p = ws + ((size_t)n * 9 + wid) * CC + 4 * (lane & 31);
    *(float4*)p = acc;
  }
}

// ---- phase 2: reduce 9 partials per ROI (4 ROIs per block) ----------------
__global__ __launch_bounds__(512)
void rroi_reduce_kernel(const float* __restrict__ ws,
                        float* __restrict__ out, int N) {
  const int n = blockIdx.x * 4 + (threadIdx.x >> 7);
  if (n >= N) return;
  const int c = threadIdx.x & 127;
  const float* p = ws + (size_t)n * 9 * CC + c;
  float s = 0.0f;
#pragma unroll
  for (int w = 0; w < 9; ++w) s += p[w * CC];
  out[(size_t)n * CC + c] = s * (1.0f / 324.0f);  // (/9 sub-boxes)*(/36 mean)
}

// ---- fallback: monolithic single-kernel (no ws needed) --------------------
__global__ __launch_bounds__(576)
void rroi_pool_kernel(const float* __restrict__ feat,
                      const float* __restrict__ rois,
                      float* __restrict__ out, int N) {
  const int n = blockIdx.x;
  const int wid  = threadIdx.x >> 6;
  const int lane = threadIdx.x & 63;
  __shared__ float partial[9][CC];

  float4 acc = make_float4(0.f, 0.f, 0.f, 0.f);
  subbox_accum4(feat, rois, n, wid, lane, acc);

  acc.x += __shfl_xor(acc.x, 32, 64);
  acc.y += __shfl_xor(acc.y, 32, 64);
  acc.z += __shfl_xor(acc.z, 32, 64);
  acc.w += __shfl_xor(acc.w, 32, 64);

  if ((lane >> 5) == 0) {
    const int cl = lane & 31;
    partial[wid][4 * cl + 0] = acc.x;
    partial[wid][4 * cl + 1] = acc.y;
    partial[wid][4 * cl + 2] = acc.z;
    partial[wid][4 * cl + 3] = acc.w;
  }
  __syncthreads();

  if (threadIdx.x < CC) {
    float s = 0.0f;
#pragma unroll
    for (int w = 0; w < 9; ++w) s += partial[w][threadIdx.x];
    out[(size_t)n * CC + threadIdx.x] = s * (1.0f / 324.0f);
  }
}

extern "C" void kernel_launch(void* const* d_in, const int* in_sizes, int n_in,
                              void* d_out, int out_size, void* d_ws, size_t ws_size,
                              hipStream_t stream) {
  const float* feat = (const float*)d_in[0];   // (4,64,96,1152) f32
  const float* rois = (const float*)d_in[1];   // (2048,5) f32
  float* out = (float*)d_out;                  // (1,2048,128) f32
  const int N = in_sizes[1] / 5;

  const size_t need = (size_t)N * 9 * CC * sizeof(float) + (size_t)N * sizeof(int);
  if (ws_size >= need && N <= 2048) {
    float* ws    = (float*)d_ws;
    int*   order = (int*)(ws + (size_t)N * 9 * CC);
    const int total = N * 9;
    const int chunk = (total + 7) / 8;                   // items per XCD
    const int blocks = chunk * 8;                        // one wave per block
    rroi_sort_kernel<<<1, 1024, 0, stream>>>(rois, order, N);
    rroi_partial_kernel<<<blocks, 64, 0, stream>>>(feat, rois, order, ws, N, chunk);
    rroi_reduce_kernel<<<(N + 3) / 4, 512, 0, stream>>>(ws, out, N);
  } else {
    rroi_pool_kernel<<<N, 576, 0, stream>>>(feat, rois, out, N);
  }
}